// Round 14
// baseline (355.023 us; speedup 1.0000x reference)
//
#include <hip/hip_runtime.h>
#include <hip/hip_bf16.h>
#include <hip/hip_fp16.h>
#include <hip/hip_fp8.h>

#define NN 25000
#define EE 400000

#define SC_UP_S 0.125f
#define SC_UP_V 0.17677669529663689f
#define Y1C 0.48860251190291992f
#define SC_MLP1 0.35355339059327373f
#define SC_MLP2 0.125f
#define SC3 0.0013020833333333333f      // (1/8)*(1/96) folded into W3
#define INV_SQRT3 0.57735026918962584f  // folded into W3 cols 64..96
#define SC_DOWN 0.025515518153991442f   // (1/4)*(1/sqrt(96)) folded into Wd
#define SC_SKIP_S 0.125f                // folded into Wssb
#define SC_SKIP_V 0.17677669529663689f  // folded into Wsvb

typedef __attribute__((ext_vector_type(8))) short short8;
typedef __attribute__((ext_vector_type(4))) float f32x4;

#if defined(__has_builtin)
#if __has_builtin(__builtin_amdgcn_cvt_pk_fp8_f32)
#define HAS_HW_FP8_ENC 1
#endif
#if __has_builtin(__builtin_amdgcn_cvt_pk_f32_fp8)
#define HAS_HW_FP8_DEC 1
#endif
#endif
#ifndef HAS_HW_FP8_ENC
#define HAS_HW_FP8_ENC 0
#endif
#ifndef HAS_HW_FP8_DEC
#define HAS_HW_FP8_DEC 0
#endif

__device__ __forceinline__ float silu(float x) {
  return __fdividef(x, 1.f + __expf(-x));
}
__device__ __forceinline__ unsigned short f2bf(float f) {
  __hip_bfloat16 h = __float2bfloat16(f);  // HW cvt, RTNE
  return *reinterpret_cast<unsigned short*>(&h);
}
__device__ __forceinline__ float bf2f(unsigned short s) {
  return __uint_as_float(((unsigned)s) << 16);
}
__device__ __forceinline__ float bfe(short8 v, int idx) {  // idx compile-time
  return __uint_as_float(((unsigned)(unsigned short)v[idx]) << 16);
}
__device__ __forceinline__ unsigned packbf(float lo, float hi) {
  return ((unsigned)f2bf(hi) << 16) | (unsigned)f2bf(lo);
}
__device__ __forceinline__ unsigned char f2fp8_sw(float x) {
  __hip_fp8_e4m3 v(x);
  return (unsigned char)v.__x;
}
__device__ __forceinline__ unsigned f2fp8x2(float a, float b) {
#if HAS_HW_FP8_ENC
  return (unsigned)__builtin_amdgcn_cvt_pk_fp8_f32(a, b, 0, false);
#else
  return (unsigned)f2fp8_sw(a) | ((unsigned)f2fp8_sw(b) << 8);
#endif
}
__device__ __forceinline__ float fp82f_sw(unsigned b) {
  __hip_fp8_e4m3 t;
  t.__x = (__hip_fp8_storage_t)b;
  return (float)t;
}
__device__ __forceinline__ void fp8x4dec(unsigned w, float* o) {
#if HAS_HW_FP8_DEC
  auto lo = __builtin_amdgcn_cvt_pk_f32_fp8((int)w, false);
  auto hi = __builtin_amdgcn_cvt_pk_f32_fp8((int)w, true);
  o[0] = lo[0]; o[1] = lo[1]; o[2] = hi[0]; o[3] = hi[1];
#else
  o[0] = fp82f_sw(w & 0xFF);
  o[1] = fp82f_sw((w >> 8) & 0xFF);
  o[2] = fp82f_sw((w >> 16) & 0xFF);
  o[3] = fp82f_sw(w >> 24);
#endif
}

// ---------------- workspace layout (4-byte word offsets) ----------------
#define W_W1P 0                         // 64x32 bf16 (K zero-padded 8->32)
#define W_W2P 1024                      // 64x64 bf16 [col][k]
#define W_W3B 3072                      // 192x64 bf16 [col][k]
#define W_WDS 9216                      // 128x96 bf16 [col][k]
#define W_WDV 15360                     // 32x96 bf16 [col][k]
#define W_WSS 16896                     // 4x64x128 bf16 (skip_s, scale folded)
#define W_WSV 33280                     // 4x32x32 bf16 (skip_v, scale folded)
#define W_SUPB 35328                    // NN*64 bf16
#define W_VUPB (W_SUPB + NN * 32)       // NN*96 bf16
#define W_DEG (W_VUPB + NN * 48)
#define W_PRE (W_DEG + NN)
#define W_CUR (W_PRE + NN + 8)
#define W_SEID (W_CUR + NN)             // sortedEid[slot] = edge id
#define W_EDN (W_SEID + EE)             // fp8: EE*224 bytes, NATURAL edge order
#define W_END (W_EDN + EE * 56)         // ~99.6 MB

// edown per-row channel layout (224 B): [0,128) scalar; 128 + o*3 + i vector

// ---------------- setup: weight transforms ----------------
__global__ __launch_bounds__(256) void transpose_weights(
    const float* __restrict__ W1, const float* __restrict__ W2,
    const float* __restrict__ W3, const float* __restrict__ Wds,
    const float* __restrict__ Wdv, const float* __restrict__ Wss,
    const float* __restrict__ Wsv, float* __restrict__ ws) {
  int t = blockIdx.x * 256 + threadIdx.x;
  int stride = gridDim.x * 256;
  unsigned short* W1p = (unsigned short*)(ws + W_W1P);
  unsigned short* W2p = (unsigned short*)(ws + W_W2P);
  unsigned short* W3b = (unsigned short*)(ws + W_W3B);
  unsigned short* Wdsb = (unsigned short*)(ws + W_WDS);
  unsigned short* Wdvb = (unsigned short*)(ws + W_WDV);
  unsigned short* Wssb = (unsigned short*)(ws + W_WSS);
  unsigned short* Wsvb = (unsigned short*)(ws + W_WSV);
  for (int i = t; i < 2048; i += stride) {  // W1p[c*32+k], k<8 real
    int c = i >> 5, k = i & 31;
    W1p[i] = (k < 8) ? f2bf(W1[k * 64 + c] * SC_MLP1) : (unsigned short)0;
  }
  for (int i = t; i < 4096; i += stride) {  // W2p[c*64+k]
    int c = i >> 6, k = i & 63;
    W2p[i] = f2bf(W2[k * 64 + c] * SC_MLP2);
  }
  for (int i = t; i < 12288; i += stride) { // W3b[c*64+k]; 1/sqrt3 fold c in [64,96)
    int c = i >> 6, k = i & 63;
    float sc = (c >= 64 && c < 96) ? (SC3 * INV_SQRT3) : SC3;
    W3b[i] = f2bf(W3[k * 192 + c] * sc);
  }
  for (int i = t; i < 12288; i += stride) { // Wdsb[o*96+k]
    int o = i / 96, k = i - 96 * o;
    Wdsb[i] = f2bf(Wds[k * 128 + o] * SC_DOWN);
  }
  for (int i = t; i < 3072; i += stride) {  // Wdvb[o*96+k]
    int o = i / 96, k = i - 96 * o;
    Wdvb[i] = f2bf(Wdv[k * 32 + o] * SC_DOWN);
  }
  for (int i = t; i < 32768; i += stride)   // Wssb: same layout, scale folded
    Wssb[i] = f2bf(Wss[i] * SC_SKIP_S);
  for (int i = t; i < 4096; i += stride)    // Wsvb
    Wsvb[i] = f2bf(Wsv[i] * SC_SKIP_V);
}

// ---------------- per-node up-projection (fp32 math, bf16 out) ----------------
__global__ __launch_bounds__(256) void up_kernel(
    const float* __restrict__ nf, const float* __restrict__ Wus,
    const float* __restrict__ Wuv, unsigned short* __restrict__ s_upb,
    unsigned short* __restrict__ v_upb) {
  int n = blockIdx.x;
  int t = threadIdx.x;
  __shared__ float sv[160];
  if (t < 160) sv[t] = nf[n * 160 + t];
  __syncthreads();
  if (t < 64) {
    float a = 0.f;
#pragma unroll
    for (int k = 0; k < 64; k++) a += sv[k] * Wus[k * 64 + t];
    s_upb[n * 64 + t] = f2bf(a * SC_UP_S);
  } else if (t < 160) {
    int j = t - 64;
    int c = j / 3, i = j - 3 * c;
    float a = 0.f;
#pragma unroll
    for (int k = 0; k < 32; k++) a += sv[64 + k * 3 + i] * Wuv[k * 32 + c];
    v_upb[n * 96 + j] = f2bf(a * SC_UP_V);
  }
}

// ---------------- counting sort (sorted edge ids) ----------------
__global__ __launch_bounds__(256) void count_deg(
    const int* __restrict__ receivers, int* __restrict__ deg) {
  int e = blockIdx.x * 256 + threadIdx.x;
  if (e < EE) atomicAdd(&deg[receivers[e]], 1);
}

__global__ __launch_bounds__(1024) void scan_kernel(
    const int* __restrict__ deg, int* __restrict__ prefix,
    int* __restrict__ cursor) {
  __shared__ int waveSums[16];
  __shared__ int sCarry;
  int t = threadIdx.x;
  int lane = t & 63, wv = t >> 6;
  if (t == 0) sCarry = 0;
  __syncthreads();
  for (int base = 0; base < NN; base += 1024) {
    int i = base + t;
    int x = (i < NN) ? deg[i] : 0;
    int v = x;
#pragma unroll
    for (int d = 1; d < 64; d <<= 1) {
      int u = __shfl_up(v, d, 64);
      if (lane >= d) v += u;
    }
    if (lane == 63) waveSums[wv] = v;
    __syncthreads();
    if (wv == 0 && lane < 16) {
      int s = waveSums[lane];
#pragma unroll
      for (int d = 1; d < 16; d <<= 1) {
        int u = __shfl_up(s, d, 64);
        if (lane >= d) s += u;
      }
      waveSums[lane] = s;
    }
    __syncthreads();
    int waveOff = (wv == 0) ? 0 : waveSums[wv - 1];
    int incl = v + waveOff + sCarry;
    if (i < NN) {
      prefix[i] = incl - x;
      cursor[i] = incl - x;
    }
    __syncthreads();
    if (t == 1023) sCarry = incl;
    __syncthreads();
  }
  if (t == 0) prefix[NN] = sCarry;
}

__global__ __launch_bounds__(256) void scatter_eid(
    const int* __restrict__ receivers, int* __restrict__ cursor,
    int* __restrict__ sortedEid) {
  int e = blockIdx.x * 256 + threadIdx.x;
  if (e < EE) {
    int r = receivers[e];
    int pos = atomicAdd(&cursor[r], 1);
    sortedEid[pos] = e;
  }
}

// ---------------- fused edge pipeline v8: natural order IN AND OUT ----------------
// Same compute as v7 but edown written at natural eid (fully coalesced burst);
// rank indirection moved to the gather's reads. sH aliases sMix (25.6KB LDS).
__global__ __launch_bounds__(256, 4) void edge_down8(
    const float* __restrict__ rbf, const float* __restrict__ vectors,
    const int* __restrict__ senders,
    const unsigned short* __restrict__ W1p,
    const unsigned short* __restrict__ W2p,
    const unsigned short* __restrict__ W3b,
    const unsigned short* __restrict__ Wdsb,
    const unsigned short* __restrict__ Wdvb,
    const unsigned short* __restrict__ s_upb,
    const unsigned short* __restrict__ v_upb,
    unsigned char* __restrict__ edown) {
  __shared__ unsigned short sMix[64 * 200];  // 25600B; aliased by sH and edL
  unsigned short* sH = sMix;                 // h1/h2, rows stride 72

  int t = threadIdx.x;
  int pbase = blockIdx.x * 64;
  int lane = t & 63;
  int wv = t >> 6;
  int rl = lane & 15;
  int kgrp = lane >> 4;
  int arow = 16 * wv + rl;        // this lane's edge row
  int crow = 16 * wv + kgrp * 4;  // C rows base (+rr)

  union S8 { short8 v; unsigned u[4]; };

  // ---- entry: coalesced ids + scattered se/ve prefetch ----
  int eid = pbase + arow;
  int snd = senders[eid];
  const unsigned short* seb = s_upb + (size_t)snd * 64;
  const unsigned short* veb = v_upb + (size_t)snd * 96;
  short8 se0 = *(const short8*)&seb[kgrp * 8];
  short8 se1 = *(const short8*)&seb[32 + kgrp * 8];
  short8 ve0 = *(const short8*)&veb[24 * kgrp];
  short8 ve1 = *(const short8*)&veb[24 * kgrp + 8];
  short8 ve2 = *(const short8*)&veb[24 * kgrp + 16];
  float vx = vectors[(size_t)eid * 3 + 0];
  float vy = vectors[(size_t)eid * 3 + 1];
  float vz = vectors[(size_t)eid * 3 + 2];
  float nrm = sqrtf(vx * vx + vy * vy + vz * vz) + 1e-12f;
  float ysc = Y1C / nrm;
  float y0 = vx * ysc, y1 = vy * ysc, y2 = vz * ysc;

  // ---- layer 1: h1 = silu(rbf @ W1), rbf coalesced ----
  S8 a1;
  a1.u[0] = a1.u[1] = a1.u[2] = a1.u[3] = 0u;
  if (kgrp == 0) {
    float4 ra = *(const float4*)(rbf + (size_t)eid * 8);
    float4 rb = *(const float4*)(rbf + (size_t)eid * 8 + 4);
    a1.u[0] = packbf(ra.x, ra.y);
    a1.u[1] = packbf(ra.z, ra.w);
    a1.u[2] = packbf(rb.x, rb.y);
    a1.u[3] = packbf(rb.z, rb.w);
  }
#pragma unroll
  for (int ct = 0; ct < 4; ct++) {
    short8 b = *(const short8*)&W1p[(ct * 16 + rl) * 32 + kgrp * 8];
    f32x4 acc = {0.f, 0.f, 0.f, 0.f};
    acc = __builtin_amdgcn_mfma_f32_16x16x32_bf16(a1.v, b, acc, 0, 0, 0);
#pragma unroll
    for (int rr = 0; rr < 4; rr++)
      sH[(crow + rr) * 72 + ct * 16 + rl] = f2bf(silu(acc[rr]));
  }

  // ---- layer 2 (wave-private rows of sH) ----
  {
    short8 a20 = *(const short8*)&sH[arow * 72 + kgrp * 8];
    short8 a21 = *(const short8*)&sH[arow * 72 + 32 + kgrp * 8];
    short8 b0s[4], b1s[4];
#pragma unroll
    for (int ct = 0; ct < 4; ct++) {
      const unsigned short* wb = &W2p[(ct * 16 + rl) * 64];
      b0s[ct] = *(const short8*)&wb[kgrp * 8];
      b1s[ct] = *(const short8*)&wb[32 + kgrp * 8];
    }
#pragma unroll
    for (int ct = 0; ct < 4; ct++) {
      f32x4 acc = {0.f, 0.f, 0.f, 0.f};
      acc = __builtin_amdgcn_mfma_f32_16x16x32_bf16(a20, b0s[ct], acc, 0, 0, 0);
      acc = __builtin_amdgcn_mfma_f32_16x16x32_bf16(a21, b1s[ct], acc, 0, 0, 0);
#pragma unroll
      for (int rr = 0; rr < 4; rr++)
        sH[(crow + rr) * 72 + ct * 16 + rl] = f2bf(silu(acc[rr]));
    }
  }

  // ---- layer 3: read h2 A-frags, BARRIER (alias), MFMA -> sMix ----
  short8 a30 = *(const short8*)&sH[arow * 72 + kgrp * 8];
  short8 a31 = *(const short8*)&sH[arow * 72 + 32 + kgrp * 8];
  __syncthreads();  // BARRIER A: all sH reads done before sMix overwrites
  {
#pragma unroll
    for (int half = 0; half < 2; half++) {
      short8 b0s[6], b1s[6];
#pragma unroll
      for (int j = 0; j < 6; j++) {
        int cc = (half * 6 + j) * 16 + rl;
        const unsigned short* wb = &W3b[cc * 64];
        b0s[j] = *(const short8*)&wb[kgrp * 8];
        b1s[j] = *(const short8*)&wb[32 + kgrp * 8];
      }
#pragma unroll
      for (int j = 0; j < 6; j++) {
        int cc = (half * 6 + j) * 16 + rl;
        f32x4 acc = {0.f, 0.f, 0.f, 0.f};
        acc = __builtin_amdgcn_mfma_f32_16x16x32_bf16(a30, b0s[j], acc, 0, 0, 0);
        acc = __builtin_amdgcn_mfma_f32_16x16x32_bf16(a31, b1s[j], acc, 0, 0, 0);
#pragma unroll
        for (int rr = 0; rr < 4; rr++)
          sMix[(crow + rr) * 200 + cc] = f2bf(acc[rr]);  // own-wave rows
      }
    }
  }

  // ---- ph3: build down-proj A-fragments in registers (own-wave sMix row) ----
  const unsigned short* mrow = &sMix[arow * 200];
  S8 as0, as1, as2, mvp1, mvp2, mvp3;
  {
    short8 m = *(const short8*)&mrow[kgrp * 8];
#pragma unroll
    for (int q = 0; q < 4; q++)
      as0.u[q] = packbf(bfe(se0, 2 * q) * bfe(m, 2 * q),
                        bfe(se0, 2 * q + 1) * bfe(m, 2 * q + 1));
  }
  {
    short8 m = *(const short8*)&mrow[32 + kgrp * 8];
#pragma unroll
    for (int q = 0; q < 4; q++)
      as1.u[q] = packbf(bfe(se1, 2 * q) * bfe(m, 2 * q),
                        bfe(se1, 2 * q + 1) * bfe(m, 2 * q + 1));
  }
  {
    short8 m = *(const short8*)&mrow[64 + kgrp * 8];
#pragma unroll
    for (int q = 0; q < 4; q++) {
      float e0, e1, e2, f0, f1, f2;
      // flat ve element j = comp (j%3) of channel kgrp*8 + j/3
      if (6 * q < 8) e0 = bfe(ve0, 6 * q); else if (6 * q < 16) e0 = bfe(ve1, 6 * q - 8); else e0 = bfe(ve2, 6 * q - 16);
      if (6 * q + 1 < 8) e1 = bfe(ve0, 6 * q + 1); else if (6 * q + 1 < 16) e1 = bfe(ve1, 6 * q - 7); else e1 = bfe(ve2, 6 * q - 15);
      if (6 * q + 2 < 8) e2 = bfe(ve0, 6 * q + 2); else if (6 * q + 2 < 16) e2 = bfe(ve1, 6 * q - 6); else e2 = bfe(ve2, 6 * q - 14);
      if (6 * q + 3 < 8) f0 = bfe(ve0, 6 * q + 3); else if (6 * q + 3 < 16) f0 = bfe(ve1, 6 * q - 5); else f0 = bfe(ve2, 6 * q - 13);
      if (6 * q + 4 < 8) f1 = bfe(ve0, 6 * q + 4); else if (6 * q + 4 < 16) f1 = bfe(ve1, 6 * q - 4); else f1 = bfe(ve2, 6 * q - 12);
      if (6 * q + 5 < 8) f2 = bfe(ve0, 6 * q + 5); else if (6 * q + 5 < 16) f2 = bfe(ve1, 6 * q - 3); else f2 = bfe(ve2, 6 * q - 11);
      float da = e0 * y0 + e1 * y1 + e2 * y2;
      float db = f0 * y0 + f1 * y1 + f2 * y2;
      as2.u[q] = packbf(da * bfe(m, 2 * q), db * bfe(m, 2 * q + 1));
    }
  }
  mvp1.v = *(const short8*)&mrow[96 + kgrp * 8];
  mvp2.v = *(const short8*)&mrow[128 + kgrp * 8];
  mvp3.v = *(const short8*)&mrow[160 + kgrp * 8];
  __syncthreads();  // BARRIER B: sMix reads done before fp8 staging aliases it

  // ---- ph4: down-proj MFMA -> fp8 (HW pk cvt) -> LDS stage (stride 232) ----
  unsigned char* edL = (unsigned char*)sMix;
#pragma unroll
  for (int half = 0; half < 2; half++) {
    short8 b0s[4], b1s[4], b2s[4];
#pragma unroll
    for (int j = 0; j < 4; j++) {
      int col = (half * 4 + j) * 16 + rl;
      const unsigned short* wb = &Wdsb[col * 96];
      b0s[j] = *(const short8*)&wb[kgrp * 8];
      b1s[j] = *(const short8*)&wb[32 + kgrp * 8];
      b2s[j] = *(const short8*)&wb[64 + kgrp * 8];
    }
#pragma unroll
    for (int j = 0; j < 4; j++) {
      int col = (half * 4 + j) * 16 + rl;
      f32x4 acc = {0.f, 0.f, 0.f, 0.f};
      acc = __builtin_amdgcn_mfma_f32_16x16x32_bf16(as0.v, b0s[j], acc, 0, 0, 0);
      acc = __builtin_amdgcn_mfma_f32_16x16x32_bf16(as1.v, b1s[j], acc, 0, 0, 0);
      acc = __builtin_amdgcn_mfma_f32_16x16x32_bf16(as2.v, b2s[j], acc, 0, 0, 0);
      unsigned p01 = f2fp8x2(acc[0], acc[1]);
      unsigned p23 = f2fp8x2(acc[2], acc[3]);
      edL[(crow + 0) * 232 + col] = (unsigned char)p01;
      edL[(crow + 1) * 232 + col] = (unsigned char)(p01 >> 8);
      edL[(crow + 2) * 232 + col] = (unsigned char)p23;
      edL[(crow + 3) * 232 + col] = (unsigned char)(p23 >> 8);
    }
  }
  float yarr[3] = {y0, y1, y2};
#pragma unroll
  for (int i = 0; i < 3; i++) {
    S8 av0, av1, av2;
#pragma unroll
    for (int q = 0; q < 4; q++) {
      float g0, g1;
      int ja = 6 * q + i, jb = 6 * q + 3 + i;  // compile-time in unrolled loop
      if (ja < 8) g0 = bfe(ve0, ja); else if (ja < 16) g0 = bfe(ve1, ja - 8); else g0 = bfe(ve2, ja - 16);
      if (jb < 8) g1 = bfe(ve0, jb); else if (jb < 16) g1 = bfe(ve1, jb - 8); else g1 = bfe(ve2, jb - 16);
      av0.u[q] = packbf(g0 * bfe(mvp1.v, 2 * q), g1 * bfe(mvp1.v, 2 * q + 1));
      av1.u[q] = packbf(bfe(se0, 2 * q) * yarr[i] * bfe(mvp2.v, 2 * q),
                        bfe(se0, 2 * q + 1) * yarr[i] * bfe(mvp2.v, 2 * q + 1));
      av2.u[q] = packbf(bfe(se1, 2 * q) * yarr[i] * bfe(mvp3.v, 2 * q),
                        bfe(se1, 2 * q + 1) * yarr[i] * bfe(mvp3.v, 2 * q + 1));
    }
#pragma unroll
    for (int ot = 0; ot < 2; ot++) {
      int o = ot * 16 + rl;
      const unsigned short* wb = &Wdvb[o * 96];
      short8 b0 = *(const short8*)&wb[kgrp * 8];
      short8 b1 = *(const short8*)&wb[32 + kgrp * 8];
      short8 b2 = *(const short8*)&wb[64 + kgrp * 8];
      f32x4 acc = {0.f, 0.f, 0.f, 0.f};
      acc = __builtin_amdgcn_mfma_f32_16x16x32_bf16(av0.v, b0, acc, 0, 0, 0);
      acc = __builtin_amdgcn_mfma_f32_16x16x32_bf16(av1.v, b1, acc, 0, 0, 0);
      acc = __builtin_amdgcn_mfma_f32_16x16x32_bf16(av2.v, b2, acc, 0, 0, 0);
      unsigned p01 = f2fp8x2(acc[0], acc[1]);
      unsigned p23 = f2fp8x2(acc[2], acc[3]);
      edL[(crow + 0) * 232 + 128 + o * 3 + i] = (unsigned char)p01;
      edL[(crow + 1) * 232 + 128 + o * 3 + i] = (unsigned char)(p01 >> 8);
      edL[(crow + 2) * 232 + 128 + o * 3 + i] = (unsigned char)p23;
      edL[(crow + 3) * 232 + 128 + o * 3 + i] = (unsigned char)(p23 >> 8);
    }
  }
  __syncthreads();  // BARRIER C: staging complete

  // coalesced NATURAL-ORDER copy-out: block writes rows pbase..pbase+64
  // as one contiguous 14336B burst (56B per lane).
  {
    int row = t >> 2, q = t & 3;
    const unsigned* src = (const unsigned*)(edL + row * 232 + q * 56);
    unsigned* dst = (unsigned*)(edown + (size_t)(pbase + row) * 224 + q * 56);
#pragma unroll
    for (int j = 0; j < 14; j++) dst[j] = src[j];
  }
}

// ---------------- gather: indirect-row streaming sum + skip + gate ----------------
__global__ __launch_bounds__(256) void gather_out6(
    const float* __restrict__ nf, const int* __restrict__ species,
    const int* __restrict__ prefix, const int* __restrict__ sortedEid,
    const unsigned char* __restrict__ edown,
    const unsigned short* __restrict__ Wssb,
    const unsigned short* __restrict__ Wsvb, float* __restrict__ out) {
  int n = blockIdx.x;
  int t = threadIdx.x;
  __shared__ float sNF[160];
  __shared__ float sPart[16 * 224];
  __shared__ float sEd[224];
  __shared__ float sF[224];
  if (t < 160) sNF[t] = nf[(size_t)n * 160 + t];
  int beg = prefix[n], end = prefix[n + 1];
  if (t < 224) {
    int u = t % 14, rg = t / 14;  // u: which uint4 of the row; rg: row group
    float a[16];
#pragma unroll
    for (int j = 0; j < 16; j++) a[j] = 0.f;
    for (int s = beg + rg; s < end; s += 16) {
      int e = sortedEid[s];
      uint4 v = *(const uint4*)(edown + (size_t)e * 224 + u * 16);
      float d[4];
      fp8x4dec(v.x, d);
      a[0] += d[0]; a[1] += d[1]; a[2] += d[2]; a[3] += d[3];
      fp8x4dec(v.y, d);
      a[4] += d[0]; a[5] += d[1]; a[6] += d[2]; a[7] += d[3];
      fp8x4dec(v.z, d);
      a[8] += d[0]; a[9] += d[1]; a[10] += d[2]; a[11] += d[3];
      fp8x4dec(v.w, d);
      a[12] += d[0]; a[13] += d[1]; a[14] += d[2]; a[15] += d[3];
    }
#pragma unroll
    for (int j = 0; j < 16; j += 4)
      *(float4*)&sPart[rg * 224 + u * 16 + j] = *(float4*)&a[j];
  }
  __syncthreads();
  if (t < 224) {
    float s = 0.f;
#pragma unroll
    for (int rg = 0; rg < 16; rg++) s += sPart[rg * 224 + t];
    sEd[t] = s;
  }
  __syncthreads();
  int spec = species[n];
  if (t < 128) {
    const unsigned short* wsk = Wssb + (size_t)spec * 8192;
    float b = 0.f;
#pragma unroll
    for (int k = 0; k < 64; k++) b += sNF[k] * bf2f(wsk[k * 128 + t]);
    sF[t] = sEd[t] + b;
  } else if (t < 224) {
    int j = t - 128;
    int c = j / 3, i = j - 3 * c;
    const unsigned short* wsk = Wsvb + (size_t)spec * 1024;
    float b = 0.f;
#pragma unroll
    for (int k = 0; k < 32; k++) b += sNF[64 + k * 3 + i] * bf2f(wsk[k * 32 + c]);
    sF[t] = sEd[t] + b;
  }
  __syncthreads();
  if (t < 96) {
    out[(size_t)n * 192 + t] = silu(sF[t]);
  } else if (t < 192) {
    int j = t - 96;
    int c = j / 3;
    out[(size_t)n * 192 + t] = sF[128 + j] * silu(sF[96 + c]);
  }
}

extern "C" void kernel_launch(void* const* d_in, const int* in_sizes, int n_in,
                              void* d_out, int out_size, void* d_ws, size_t ws_size,
                              hipStream_t stream) {
  const float* nf = (const float*)d_in[0];
  const float* vectors = (const float*)d_in[1];
  const float* rbf = (const float*)d_in[2];
  const int* species = (const int*)d_in[3];
  const int* senders = (const int*)d_in[4];
  const int* receivers = (const int*)d_in[5];
  const float* Wus = (const float*)d_in[6];
  const float* Wuv = (const float*)d_in[7];
  const float* W1 = (const float*)d_in[8];
  const float* W2 = (const float*)d_in[9];
  const float* W3 = (const float*)d_in[10];
  const float* Wds = (const float*)d_in[11];
  const float* Wdv = (const float*)d_in[12];
  const float* Wss = (const float*)d_in[13];
  const float* Wsv = (const float*)d_in[14];

  float* ws = (float*)d_ws;
  const unsigned short* W1p = (const unsigned short*)(ws + W_W1P);
  const unsigned short* W2p = (const unsigned short*)(ws + W_W2P);
  const unsigned short* W3b = (const unsigned short*)(ws + W_W3B);
  const unsigned short* Wdsb = (const unsigned short*)(ws + W_WDS);
  const unsigned short* Wdvb = (const unsigned short*)(ws + W_WDV);
  const unsigned short* Wssb = (const unsigned short*)(ws + W_WSS);
  const unsigned short* Wsvb = (const unsigned short*)(ws + W_WSV);
  unsigned short* s_upb = (unsigned short*)(ws + W_SUPB);
  unsigned short* v_upb = (unsigned short*)(ws + W_VUPB);
  int* deg = (int*)(ws + W_DEG);
  int* prefix = (int*)(ws + W_PRE);
  int* cursor = (int*)(ws + W_CUR);
  int* sortedEid = (int*)(ws + W_SEID);
  unsigned char* edown = (unsigned char*)(ws + W_EDN);
  float* out = (float*)d_out;

  transpose_weights<<<16, 256, 0, stream>>>(W1, W2, W3, Wds, Wdv, Wss, Wsv, ws);
  up_kernel<<<NN, 256, 0, stream>>>(nf, Wus, Wuv, s_upb, v_upb);

  hipMemsetAsync(deg, 0, (size_t)NN * sizeof(int), stream);
  count_deg<<<(EE + 255) / 256, 256, 0, stream>>>(receivers, deg);
  scan_kernel<<<1, 1024, 0, stream>>>(deg, prefix, cursor);
  scatter_eid<<<(EE + 255) / 256, 256, 0, stream>>>(receivers, cursor,
                                                    sortedEid);
  edge_down8<<<EE / 64, 256, 0, stream>>>(rbf, vectors, senders, W1p, W2p, W3b,
                                          Wdsb, Wdvb, s_upb, v_upb, edown);
  gather_out6<<<NN, 256, 0, stream>>>(nf, species, prefix, sortedEid, edown,
                                      Wssb, Wsvb, out);
}

// Round 15
// 336.384 us; speedup vs baseline: 1.0554x; 1.0554x over previous
//
#include <hip/hip_runtime.h>
#include <hip/hip_bf16.h>
#include <hip/hip_fp16.h>
#include <hip/hip_fp8.h>

#define NN 25000
#define EE 400000

#define SC_UP_S 0.125f
#define SC_UP_V 0.17677669529663689f
#define Y1C 0.48860251190291992f
#define SC_MLP1 0.35355339059327373f
#define SC_MLP2 0.125f
#define SC3 0.0013020833333333333f      // (1/8)*(1/96) folded into W3
#define INV_SQRT3 0.57735026918962584f  // folded into W3 cols 64..96
#define SC_DOWN 0.025515518153991442f   // (1/4)*(1/sqrt(96)) folded into Wd
#define SC_SKIP_S 0.125f                // folded into Wssb
#define SC_SKIP_V 0.17677669529663689f  // folded into Wsvb

typedef __attribute__((ext_vector_type(8))) short short8;
typedef __attribute__((ext_vector_type(4))) float f32x4;

#if defined(__has_builtin)
#if __has_builtin(__builtin_amdgcn_cvt_pk_fp8_f32)
#define HAS_HW_FP8_ENC 1
#endif
#if __has_builtin(__builtin_amdgcn_cvt_pk_f32_fp8)
#define HAS_HW_FP8_DEC 1
#endif
#endif
#ifndef HAS_HW_FP8_ENC
#define HAS_HW_FP8_ENC 0
#endif
#ifndef HAS_HW_FP8_DEC
#define HAS_HW_FP8_DEC 0
#endif

__device__ __forceinline__ float silu(float x) {
  return __fdividef(x, 1.f + __expf(-x));
}
__device__ __forceinline__ unsigned short f2bf(float f) {
  __hip_bfloat16 h = __float2bfloat16(f);  // HW cvt, RTNE
  return *reinterpret_cast<unsigned short*>(&h);
}
__device__ __forceinline__ float bf2f(unsigned short s) {
  return __uint_as_float(((unsigned)s) << 16);
}
__device__ __forceinline__ float bfe(short8 v, int idx) {  // idx compile-time
  return __uint_as_float(((unsigned)(unsigned short)v[idx]) << 16);
}
__device__ __forceinline__ unsigned packbf(float lo, float hi) {
  return ((unsigned)f2bf(hi) << 16) | (unsigned)f2bf(lo);
}
__device__ __forceinline__ unsigned char f2fp8_sw(float x) {
  __hip_fp8_e4m3 v(x);
  return (unsigned char)v.__x;
}
__device__ __forceinline__ unsigned f2fp8x2(float a, float b) {
#if HAS_HW_FP8_ENC
  return (unsigned)__builtin_amdgcn_cvt_pk_fp8_f32(a, b, 0, false);
#else
  return (unsigned)f2fp8_sw(a) | ((unsigned)f2fp8_sw(b) << 8);
#endif
}
__device__ __forceinline__ float fp82f_sw(unsigned b) {
  __hip_fp8_e4m3 t;
  t.__x = (__hip_fp8_storage_t)b;
  return (float)t;
}
__device__ __forceinline__ void fp8x4dec(unsigned w, float* o) {
#if HAS_HW_FP8_DEC
  auto lo = __builtin_amdgcn_cvt_pk_f32_fp8((int)w, false);
  auto hi = __builtin_amdgcn_cvt_pk_f32_fp8((int)w, true);
  o[0] = lo[0]; o[1] = lo[1]; o[2] = hi[0]; o[3] = hi[1];
#else
  o[0] = fp82f_sw(w & 0xFF);
  o[1] = fp82f_sw((w >> 8) & 0xFF);
  o[2] = fp82f_sw((w >> 16) & 0xFF);
  o[3] = fp82f_sw(w >> 24);
#endif
}

// ---------------- workspace layout (4-byte word offsets) ----------------
#define W_W1P 0                         // 64x32 bf16 (K zero-padded 8->32)
#define W_W2P 1024                      // 64x64 bf16 [col][k]
#define W_W3B 3072                      // 192x64 bf16 [col][k]
#define W_WDS 9216                      // 128x96 bf16 [col][k]
#define W_WDV 15360                     // 32x96 bf16 [col][k]
#define W_WSS 16896                     // 4x64x128 bf16 (skip_s, scale folded)
#define W_WSV 33280                     // 4x32x32 bf16 (skip_v, scale folded)
#define W_SUPB 35328                    // NN*64 bf16
#define W_VUPB (W_SUPB + NN * 32)       // NN*96 bf16
#define W_DEG (W_VUPB + NN * 48)
#define W_PRE (W_DEG + NN)
#define W_CUR (W_PRE + NN + 8)
#define W_RNK (W_CUR + NN)              // rank[e] = sorted position
#define W_EDN (W_RNK + EE)              // fp8: EE*224 bytes (sorted order)
#define W_END (W_EDN + EE * 56)         // ~99.6 MB

// edown per-row channel layout (224 B): [0,128) scalar; 128 + o*3 + i vector

// ---------------- fused setup: weight transforms + degree count ----------------
__global__ __launch_bounds__(256) void setup_count(
    const float* __restrict__ W1, const float* __restrict__ W2,
    const float* __restrict__ W3, const float* __restrict__ Wds,
    const float* __restrict__ Wdv, const float* __restrict__ Wss,
    const float* __restrict__ Wsv, float* __restrict__ ws,
    const int* __restrict__ receivers, int* __restrict__ deg) {
  int t = blockIdx.x * 256 + threadIdx.x;
  int stride = gridDim.x * 256;
  unsigned short* W1p = (unsigned short*)(ws + W_W1P);
  unsigned short* W2p = (unsigned short*)(ws + W_W2P);
  unsigned short* W3b = (unsigned short*)(ws + W_W3B);
  unsigned short* Wdsb = (unsigned short*)(ws + W_WDS);
  unsigned short* Wdvb = (unsigned short*)(ws + W_WDV);
  unsigned short* Wssb = (unsigned short*)(ws + W_WSS);
  unsigned short* Wsvb = (unsigned short*)(ws + W_WSV);
  for (int i = t; i < 2048; i += stride) {  // W1p[c*32+k], k<8 real
    int c = i >> 5, k = i & 31;
    W1p[i] = (k < 8) ? f2bf(W1[k * 64 + c] * SC_MLP1) : (unsigned short)0;
  }
  for (int i = t; i < 4096; i += stride) {  // W2p[c*64+k]
    int c = i >> 6, k = i & 63;
    W2p[i] = f2bf(W2[k * 64 + c] * SC_MLP2);
  }
  for (int i = t; i < 12288; i += stride) { // W3b[c*64+k]; 1/sqrt3 fold c in [64,96)
    int c = i >> 6, k = i & 63;
    float sc = (c >= 64 && c < 96) ? (SC3 * INV_SQRT3) : SC3;
    W3b[i] = f2bf(W3[k * 192 + c] * sc);
  }
  for (int i = t; i < 12288; i += stride) { // Wdsb[o*96+k]
    int o = i / 96, k = i - 96 * o;
    Wdsb[i] = f2bf(Wds[k * 128 + o] * SC_DOWN);
  }
  for (int i = t; i < 3072; i += stride) {  // Wdvb[o*96+k]
    int o = i / 96, k = i - 96 * o;
    Wdvb[i] = f2bf(Wdv[k * 32 + o] * SC_DOWN);
  }
  for (int i = t; i < 32768; i += stride)   // Wssb: same layout, scale folded
    Wssb[i] = f2bf(Wss[i] * SC_SKIP_S);
  for (int i = t; i < 4096; i += stride)    // Wsvb
    Wsvb[i] = f2bf(Wsv[i] * SC_SKIP_V);
  if (t < EE) atomicAdd(&deg[receivers[t]], 1);
}

// ---------------- per-node up-projection, 2 nodes per block ----------------
__global__ __launch_bounds__(256) void up_kernel2(
    const float* __restrict__ nf, const float* __restrict__ Wus,
    const float* __restrict__ Wuv, unsigned short* __restrict__ s_upb,
    unsigned short* __restrict__ v_upb) {
  int t = threadIdx.x;
  __shared__ float sv[160];
#pragma unroll
  for (int nn = 0; nn < 2; nn++) {
    int n = blockIdx.x * 2 + nn;
    if (n >= NN) break;
    __syncthreads();
    if (t < 160) sv[t] = nf[(size_t)n * 160 + t];
    __syncthreads();
    if (t < 64) {
      float a = 0.f;
#pragma unroll
      for (int k = 0; k < 64; k++) a += sv[k] * Wus[k * 64 + t];
      s_upb[(size_t)n * 64 + t] = f2bf(a * SC_UP_S);
    } else if (t < 160) {
      int j = t - 64;
      int c = j / 3, i = j - 3 * c;
      float a = 0.f;
#pragma unroll
      for (int k = 0; k < 32; k++) a += sv[64 + k * 3 + i] * Wuv[k * 32 + c];
      v_upb[(size_t)n * 96 + j] = f2bf(a * SC_UP_V);
    }
  }
}

// ---------------- scan (prefix + cursor) ----------------
__global__ __launch_bounds__(1024) void scan_kernel(
    const int* __restrict__ deg, int* __restrict__ prefix,
    int* __restrict__ cursor) {
  __shared__ int waveSums[16];
  __shared__ int sCarry;
  int t = threadIdx.x;
  int lane = t & 63, wv = t >> 6;
  if (t == 0) sCarry = 0;
  __syncthreads();
  for (int base = 0; base < NN; base += 1024) {
    int i = base + t;
    int x = (i < NN) ? deg[i] : 0;
    int v = x;
#pragma unroll
    for (int d = 1; d < 64; d <<= 1) {
      int u = __shfl_up(v, d, 64);
      if (lane >= d) v += u;
    }
    if (lane == 63) waveSums[wv] = v;
    __syncthreads();
    if (wv == 0 && lane < 16) {
      int s = waveSums[lane];
#pragma unroll
      for (int d = 1; d < 16; d <<= 1) {
        int u = __shfl_up(s, d, 64);
        if (lane >= d) s += u;
      }
      waveSums[lane] = s;
    }
    __syncthreads();
    int waveOff = (wv == 0) ? 0 : waveSums[wv - 1];
    int incl = v + waveOff + sCarry;
    if (i < NN) {
      prefix[i] = incl - x;
      cursor[i] = incl - x;
    }
    __syncthreads();
    if (t == 1023) sCarry = incl;
    __syncthreads();
  }
  if (t == 0) prefix[NN] = sCarry;
}

__global__ __launch_bounds__(256) void rank_kernel(
    const int* __restrict__ receivers, int* __restrict__ cursor,
    int* __restrict__ rankArr) {
  int e = blockIdx.x * 256 + threadIdx.x;
  if (e < EE) {
    int r = receivers[e];
    rankArr[e] = atomicAdd(&cursor[r], 1);
  }
}

// ---------------- fused edge pipeline (r10-proven edge_down4) ----------------
// Natural edge order in; LDS fp8 staging; contiguous 224B/row rank-scatter out.
// sH and sMix SEPARATE (35.3KB LDS, 4 blocks/CU) — proven clean write merge.
__global__ __launch_bounds__(256, 4) void edge_down4(
    const float* __restrict__ rbf, const float* __restrict__ vectors,
    const int* __restrict__ senders, const int* __restrict__ rankArr,
    const unsigned short* __restrict__ W1p,
    const unsigned short* __restrict__ W2p,
    const unsigned short* __restrict__ W3b,
    const unsigned short* __restrict__ Wdsb,
    const unsigned short* __restrict__ Wdvb,
    const unsigned short* __restrict__ s_upb,
    const unsigned short* __restrict__ v_upb,
    unsigned char* __restrict__ edown) {
  __shared__ unsigned short sH[64 * 72];     // h1 then h2 (wave-private rows)
  __shared__ unsigned short sMix[64 * 200];  // mix; then fp8 staging (stride 232B)
  __shared__ int sRank[64];

  int t = threadIdx.x;
  int pbase = blockIdx.x * 64;
  int lane = t & 63;
  int wv = t >> 6;
  int rl = lane & 15;
  int kgrp = lane >> 4;
  int arow = 16 * wv + rl;        // this lane's edge row
  int crow = 16 * wv + kgrp * 4;  // C rows base (+rr)

  union S8 { short8 v; unsigned u[4]; };

  // ---- entry: coalesced ids + scattered se/ve prefetch ----
  if (t < 64) sRank[t] = rankArr[pbase + t];
  int eid = pbase + arow;
  int snd = senders[eid];
  const unsigned short* seb = s_upb + (size_t)snd * 64;
  const unsigned short* veb = v_upb + (size_t)snd * 96;
  short8 se0 = *(const short8*)&seb[kgrp * 8];
  short8 se1 = *(const short8*)&seb[32 + kgrp * 8];
  short8 ve0 = *(const short8*)&veb[24 * kgrp];
  short8 ve1 = *(const short8*)&veb[24 * kgrp + 8];
  short8 ve2 = *(const short8*)&veb[24 * kgrp + 16];
  float vx = vectors[(size_t)eid * 3 + 0];
  float vy = vectors[(size_t)eid * 3 + 1];
  float vz = vectors[(size_t)eid * 3 + 2];
  float nrm = sqrtf(vx * vx + vy * vy + vz * vz) + 1e-12f;
  float ysc = Y1C / nrm;
  float y0 = vx * ysc, y1 = vy * ysc, y2 = vz * ysc;

  // ---- layer 1: h1 = silu(rbf @ W1), rbf coalesced ----
  S8 a1;
  a1.u[0] = a1.u[1] = a1.u[2] = a1.u[3] = 0u;
  if (kgrp == 0) {
    float4 ra = *(const float4*)(rbf + (size_t)eid * 8);
    float4 rb = *(const float4*)(rbf + (size_t)eid * 8 + 4);
    a1.u[0] = packbf(ra.x, ra.y);
    a1.u[1] = packbf(ra.z, ra.w);
    a1.u[2] = packbf(rb.x, rb.y);
    a1.u[3] = packbf(rb.z, rb.w);
  }
#pragma unroll
  for (int ct = 0; ct < 4; ct++) {
    short8 b = *(const short8*)&W1p[(ct * 16 + rl) * 32 + kgrp * 8];
    f32x4 acc = {0.f, 0.f, 0.f, 0.f};
    acc = __builtin_amdgcn_mfma_f32_16x16x32_bf16(a1.v, b, acc, 0, 0, 0);
#pragma unroll
    for (int rr = 0; rr < 4; rr++)
      sH[(crow + rr) * 72 + ct * 16 + rl] = f2bf(silu(acc[rr]));
  }

  // ---- layer 2 ----
  {
    short8 a20 = *(const short8*)&sH[arow * 72 + kgrp * 8];
    short8 a21 = *(const short8*)&sH[arow * 72 + 32 + kgrp * 8];
    short8 b0s[4], b1s[4];
#pragma unroll
    for (int ct = 0; ct < 4; ct++) {
      const unsigned short* wb = &W2p[(ct * 16 + rl) * 64];
      b0s[ct] = *(const short8*)&wb[kgrp * 8];
      b1s[ct] = *(const short8*)&wb[32 + kgrp * 8];
    }
#pragma unroll
    for (int ct = 0; ct < 4; ct++) {
      f32x4 acc = {0.f, 0.f, 0.f, 0.f};
      acc = __builtin_amdgcn_mfma_f32_16x16x32_bf16(a20, b0s[ct], acc, 0, 0, 0);
      acc = __builtin_amdgcn_mfma_f32_16x16x32_bf16(a21, b1s[ct], acc, 0, 0, 0);
#pragma unroll
      for (int rr = 0; rr < 4; rr++)
        sH[(crow + rr) * 72 + ct * 16 + rl] = f2bf(silu(acc[rr]));
    }
  }

  // ---- layer 3: mix -> sMix (wave-private rows), chunked B preload ----
  {
    short8 a30 = *(const short8*)&sH[arow * 72 + kgrp * 8];
    short8 a31 = *(const short8*)&sH[arow * 72 + 32 + kgrp * 8];
#pragma unroll
    for (int half = 0; half < 2; half++) {
      short8 b0s[6], b1s[6];
#pragma unroll
      for (int j = 0; j < 6; j++) {
        int cc = (half * 6 + j) * 16 + rl;
        const unsigned short* wb = &W3b[cc * 64];
        b0s[j] = *(const short8*)&wb[kgrp * 8];
        b1s[j] = *(const short8*)&wb[32 + kgrp * 8];
      }
#pragma unroll
      for (int j = 0; j < 6; j++) {
        int cc = (half * 6 + j) * 16 + rl;
        f32x4 acc = {0.f, 0.f, 0.f, 0.f};
        acc = __builtin_amdgcn_mfma_f32_16x16x32_bf16(a30, b0s[j], acc, 0, 0, 0);
        acc = __builtin_amdgcn_mfma_f32_16x16x32_bf16(a31, b1s[j], acc, 0, 0, 0);
#pragma unroll
        for (int rr = 0; rr < 4; rr++)
          sMix[(crow + rr) * 200 + cc] = f2bf(acc[rr]);
      }
    }
  }

  // ---- ph3: build down-proj A-fragments in registers ----
  const unsigned short* mrow = &sMix[arow * 200];
  S8 as0, as1, as2, mvp1, mvp2, mvp3;
  {
    short8 m = *(const short8*)&mrow[kgrp * 8];
#pragma unroll
    for (int q = 0; q < 4; q++)
      as0.u[q] = packbf(bfe(se0, 2 * q) * bfe(m, 2 * q),
                        bfe(se0, 2 * q + 1) * bfe(m, 2 * q + 1));
  }
  {
    short8 m = *(const short8*)&mrow[32 + kgrp * 8];
#pragma unroll
    for (int q = 0; q < 4; q++)
      as1.u[q] = packbf(bfe(se1, 2 * q) * bfe(m, 2 * q),
                        bfe(se1, 2 * q + 1) * bfe(m, 2 * q + 1));
  }
  {
    short8 m = *(const short8*)&mrow[64 + kgrp * 8];
#pragma unroll
    for (int q = 0; q < 4; q++) {
      float e0, e1, e2, f0, f1, f2;
      // flat ve element j = comp (j%3) of channel kgrp*8 + j/3
      if (6 * q < 8) e0 = bfe(ve0, 6 * q); else if (6 * q < 16) e0 = bfe(ve1, 6 * q - 8); else e0 = bfe(ve2, 6 * q - 16);
      if (6 * q + 1 < 8) e1 = bfe(ve0, 6 * q + 1); else if (6 * q + 1 < 16) e1 = bfe(ve1, 6 * q - 7); else e1 = bfe(ve2, 6 * q - 15);
      if (6 * q + 2 < 8) e2 = bfe(ve0, 6 * q + 2); else if (6 * q + 2 < 16) e2 = bfe(ve1, 6 * q - 6); else e2 = bfe(ve2, 6 * q - 14);
      if (6 * q + 3 < 8) f0 = bfe(ve0, 6 * q + 3); else if (6 * q + 3 < 16) f0 = bfe(ve1, 6 * q - 5); else f0 = bfe(ve2, 6 * q - 13);
      if (6 * q + 4 < 8) f1 = bfe(ve0, 6 * q + 4); else if (6 * q + 4 < 16) f1 = bfe(ve1, 6 * q - 4); else f1 = bfe(ve2, 6 * q - 12);
      if (6 * q + 5 < 8) f2 = bfe(ve0, 6 * q + 5); else if (6 * q + 5 < 16) f2 = bfe(ve1, 6 * q - 3); else f2 = bfe(ve2, 6 * q - 11);
      float da = e0 * y0 + e1 * y1 + e2 * y2;
      float db = f0 * y0 + f1 * y1 + f2 * y2;
      as2.u[q] = packbf(da * bfe(m, 2 * q), db * bfe(m, 2 * q + 1));
    }
  }
  mvp1.v = *(const short8*)&mrow[96 + kgrp * 8];
  mvp2.v = *(const short8*)&mrow[128 + kgrp * 8];
  mvp3.v = *(const short8*)&mrow[160 + kgrp * 8];
  __syncthreads();  // BARRIER 1: sMix reads done before fp8 staging aliases it

  // ---- ph4: down-proj MFMA -> fp8 (HW pk cvt) -> LDS stage (stride 232) ----
  unsigned char* edL = (unsigned char*)sMix;
#pragma unroll
  for (int half = 0; half < 2; half++) {
    short8 b0s[4], b1s[4], b2s[4];
#pragma unroll
    for (int j = 0; j < 4; j++) {
      int col = (half * 4 + j) * 16 + rl;
      const unsigned short* wb = &Wdsb[col * 96];
      b0s[j] = *(const short8*)&wb[kgrp * 8];
      b1s[j] = *(const short8*)&wb[32 + kgrp * 8];
      b2s[j] = *(const short8*)&wb[64 + kgrp * 8];
    }
#pragma unroll
    for (int j = 0; j < 4; j++) {
      int col = (half * 4 + j) * 16 + rl;
      f32x4 acc = {0.f, 0.f, 0.f, 0.f};
      acc = __builtin_amdgcn_mfma_f32_16x16x32_bf16(as0.v, b0s[j], acc, 0, 0, 0);
      acc = __builtin_amdgcn_mfma_f32_16x16x32_bf16(as1.v, b1s[j], acc, 0, 0, 0);
      acc = __builtin_amdgcn_mfma_f32_16x16x32_bf16(as2.v, b2s[j], acc, 0, 0, 0);
      unsigned p01 = f2fp8x2(acc[0], acc[1]);
      unsigned p23 = f2fp8x2(acc[2], acc[3]);
      edL[(crow + 0) * 232 + col] = (unsigned char)p01;
      edL[(crow + 1) * 232 + col] = (unsigned char)(p01 >> 8);
      edL[(crow + 2) * 232 + col] = (unsigned char)p23;
      edL[(crow + 3) * 232 + col] = (unsigned char)(p23 >> 8);
    }
  }
  float yarr[3] = {y0, y1, y2};
#pragma unroll
  for (int i = 0; i < 3; i++) {
    S8 av0, av1, av2;
#pragma unroll
    for (int q = 0; q < 4; q++) {
      float g0, g1;
      int ja = 6 * q + i, jb = 6 * q + 3 + i;  // compile-time in unrolled loop
      if (ja < 8) g0 = bfe(ve0, ja); else if (ja < 16) g0 = bfe(ve1, ja - 8); else g0 = bfe(ve2, ja - 16);
      if (jb < 8) g1 = bfe(ve0, jb); else if (jb < 16) g1 = bfe(ve1, jb - 8); else g1 = bfe(ve2, jb - 16);
      av0.u[q] = packbf(g0 * bfe(mvp1.v, 2 * q), g1 * bfe(mvp1.v, 2 * q + 1));
      av1.u[q] = packbf(bfe(se0, 2 * q) * yarr[i] * bfe(mvp2.v, 2 * q),
                        bfe(se0, 2 * q + 1) * yarr[i] * bfe(mvp2.v, 2 * q + 1));
      av2.u[q] = packbf(bfe(se1, 2 * q) * yarr[i] * bfe(mvp3.v, 2 * q),
                        bfe(se1, 2 * q + 1) * yarr[i] * bfe(mvp3.v, 2 * q + 1));
    }
#pragma unroll
    for (int ot = 0; ot < 2; ot++) {
      int o = ot * 16 + rl;
      const unsigned short* wb = &Wdvb[o * 96];
      short8 b0 = *(const short8*)&wb[kgrp * 8];
      short8 b1 = *(const short8*)&wb[32 + kgrp * 8];
      short8 b2 = *(const short8*)&wb[64 + kgrp * 8];
      f32x4 acc = {0.f, 0.f, 0.f, 0.f};
      acc = __builtin_amdgcn_mfma_f32_16x16x32_bf16(av0.v, b0, acc, 0, 0, 0);
      acc = __builtin_amdgcn_mfma_f32_16x16x32_bf16(av1.v, b1, acc, 0, 0, 0);
      acc = __builtin_amdgcn_mfma_f32_16x16x32_bf16(av2.v, b2, acc, 0, 0, 0);
      unsigned p01 = f2fp8x2(acc[0], acc[1]);
      unsigned p23 = f2fp8x2(acc[2], acc[3]);
      edL[(crow + 0) * 232 + 128 + o * 3 + i] = (unsigned char)p01;
      edL[(crow + 1) * 232 + 128 + o * 3 + i] = (unsigned char)(p01 >> 8);
      edL[(crow + 2) * 232 + 128 + o * 3 + i] = (unsigned char)p23;
      edL[(crow + 3) * 232 + 128 + o * 3 + i] = (unsigned char)(p23 >> 8);
    }
  }
  __syncthreads();  // BARRIER 2: staging + sRank complete

  // rank-scatter copy-out: row r -> edown[rank*224], contiguous 56B per lane
  {
    int row = t >> 2, q = t & 3;
    const unsigned* src = (const unsigned*)(edL + row * 232 + q * 56);
    unsigned* dst = (unsigned*)(edown + (size_t)sRank[row] * 224 + q * 56);
#pragma unroll
    for (int j = 0; j < 14; j++) dst[j] = src[j];
  }
}

// ---------------- gather: uint4 streaming segmented sum + skip + gate ----------------
__global__ __launch_bounds__(256) void gather_out4(
    const float* __restrict__ nf, const int* __restrict__ species,
    const int* __restrict__ prefix, const unsigned char* __restrict__ edown,
    const unsigned short* __restrict__ Wssb,
    const unsigned short* __restrict__ Wsvb, float* __restrict__ out) {
  int n = blockIdx.x;
  int t = threadIdx.x;
  __shared__ float sNF[160];
  __shared__ float sPart[16 * 224];
  __shared__ float sEd[224];
  __shared__ float sF[224];
  if (t < 160) sNF[t] = nf[(size_t)n * 160 + t];
  int beg = prefix[n], end = prefix[n + 1];
  if (t < 224) {
    int u = t % 14, rg = t / 14;  // u: which uint4 of the row; rg: row group
    float a[16];
#pragma unroll
    for (int j = 0; j < 16; j++) a[j] = 0.f;
    for (int s = beg + rg; s < end; s += 16) {
      uint4 v = *(const uint4*)(edown + (size_t)s * 224 + u * 16);
      float d[4];
      fp8x4dec(v.x, d);
      a[0] += d[0]; a[1] += d[1]; a[2] += d[2]; a[3] += d[3];
      fp8x4dec(v.y, d);
      a[4] += d[0]; a[5] += d[1]; a[6] += d[2]; a[7] += d[3];
      fp8x4dec(v.z, d);
      a[8] += d[0]; a[9] += d[1]; a[10] += d[2]; a[11] += d[3];
      fp8x4dec(v.w, d);
      a[12] += d[0]; a[13] += d[1]; a[14] += d[2]; a[15] += d[3];
    }
#pragma unroll
    for (int j = 0; j < 16; j += 4)
      *(float4*)&sPart[rg * 224 + u * 16 + j] = *(float4*)&a[j];
  }
  __syncthreads();
  if (t < 224) {
    float s = 0.f;
#pragma unroll
    for (int rg = 0; rg < 16; rg++) s += sPart[rg * 224 + t];
    sEd[t] = s;
  }
  __syncthreads();
  int spec = species[n];
  if (t < 128) {
    const unsigned short* wsk = Wssb + (size_t)spec * 8192;
    float b = 0.f;
#pragma unroll
    for (int k = 0; k < 64; k++) b += sNF[k] * bf2f(wsk[k * 128 + t]);
    sF[t] = sEd[t] + b;
  } else if (t < 224) {
    int j = t - 128;
    int c = j / 3, i = j - 3 * c;
    const unsigned short* wsk = Wsvb + (size_t)spec * 1024;
    float b = 0.f;
#pragma unroll
    for (int k = 0; k < 32; k++) b += sNF[64 + k * 3 + i] * bf2f(wsk[k * 32 + c]);
    sF[t] = sEd[t] + b;
  }
  __syncthreads();
  if (t < 96) {
    out[(size_t)n * 192 + t] = silu(sF[t]);
  } else if (t < 192) {
    int j = t - 96;
    int c = j / 3;
    out[(size_t)n * 192 + t] = sF[128 + j] * silu(sF[96 + c]);
  }
}

extern "C" void kernel_launch(void* const* d_in, const int* in_sizes, int n_in,
                              void* d_out, int out_size, void* d_ws, size_t ws_size,
                              hipStream_t stream) {
  const float* nf = (const float*)d_in[0];
  const float* vectors = (const float*)d_in[1];
  const float* rbf = (const float*)d_in[2];
  const int* species = (const int*)d_in[3];
  const int* senders = (const int*)d_in[4];
  const int* receivers = (const int*)d_in[5];
  const float* Wus = (const float*)d_in[6];
  const float* Wuv = (const float*)d_in[7];
  const float* W1 = (const float*)d_in[8];
  const float* W2 = (const float*)d_in[9];
  const float* W3 = (const float*)d_in[10];
  const float* Wds = (const float*)d_in[11];
  const float* Wdv = (const float*)d_in[12];
  const float* Wss = (const float*)d_in[13];
  const float* Wsv = (const float*)d_in[14];

  float* ws = (float*)d_ws;
  const unsigned short* W1p = (const unsigned short*)(ws + W_W1P);
  const unsigned short* W2p = (const unsigned short*)(ws + W_W2P);
  const unsigned short* W3b = (const unsigned short*)(ws + W_W3B);
  const unsigned short* Wdsb = (const unsigned short*)(ws + W_WDS);
  const unsigned short* Wdvb = (const unsigned short*)(ws + W_WDV);
  const unsigned short* Wssb = (const unsigned short*)(ws + W_WSS);
  const unsigned short* Wsvb = (const unsigned short*)(ws + W_WSV);
  unsigned short* s_upb = (unsigned short*)(ws + W_SUPB);
  unsigned short* v_upb = (unsigned short*)(ws + W_VUPB);
  int* deg = (int*)(ws + W_DEG);
  int* prefix = (int*)(ws + W_PRE);
  int* cursor = (int*)(ws + W_CUR);
  int* rankArr = (int*)(ws + W_RNK);
  unsigned char* edown = (unsigned char*)(ws + W_EDN);
  float* out = (float*)d_out;

  hipMemsetAsync(deg, 0, (size_t)NN * sizeof(int), stream);
  setup_count<<<(EE + 255) / 256, 256, 0, stream>>>(
      W1, W2, W3, Wds, Wdv, Wss, Wsv, ws, receivers, deg);
  up_kernel2<<<(NN + 1) / 2, 256, 0, stream>>>(nf, Wus, Wuv, s_upb, v_upb);
  scan_kernel<<<1, 1024, 0, stream>>>(deg, prefix, cursor);
  rank_kernel<<<(EE + 255) / 256, 256, 0, stream>>>(receivers, cursor, rankArr);
  edge_down4<<<EE / 64, 256, 0, stream>>>(rbf, vectors, senders, rankArr, W1p,
                                          W2p, W3b, Wdsb, Wdvb, s_upb, v_upb,
                                          edown);
  gather_out4<<<NN, 256, 0, stream>>>(nf, species, prefix, edown, Wssb, Wsvb,
                                      out);
}